// Round 1
// baseline (57.990 us; speedup 1.0000x reference)
//
#include <hip/hip_runtime.h>
#include <hip/hip_bf16.h>

#define NB 16
#define NN 256
#define NH 8
#define ND 64
#define NT 5

typedef __bf16 bf16x8 __attribute__((ext_vector_type(8)));
typedef float  f32x4  __attribute__((ext_vector_type(4)));

__device__ __forceinline__ bf16x8 load8f_bf16(const float* __restrict__ p) {
    const float4 a = *reinterpret_cast<const float4*>(p);
    const float4 b = *reinterpret_cast<const float4*>(p + 4);
    bf16x8 r;
    r[0] = (__bf16)a.x; r[1] = (__bf16)a.y; r[2] = (__bf16)a.z; r[3] = (__bf16)a.w;
    r[4] = (__bf16)b.x; r[5] = (__bf16)b.y; r[6] = (__bf16)b.z; r[7] = (__bf16)b.w;
    return r;
}

// Transpose a[(h*64+dd)*64*5 + e*5 + t] (fp32) -> wt[h][t][e][dd] (bf16).
// idx is input-linear => fully coalesced reads; scattered 2B writes (tiny, one-shot).
__global__ void prep_w_kernel(const float* __restrict__ a, __bf16* __restrict__ wt) {
    int idx = blockIdx.x * 256 + threadIdx.x;
    if (idx >= NH * ND * ND * NT) return;
    int t  = idx % NT;
    int e  = (idx / NT) % ND;
    int dd = (idx / (NT * ND)) % ND;
    int h  = idx / (NT * ND * ND);
    wt[(((h * NT + t) * ND + e) * ND) + dd] = (__bf16)a[idx];
}

template <bool USE_WT>
__global__ __launch_bounds__(256) void mhea_kernel(
    const float* __restrict__ src, const float* __restrict__ dst,
    const float* __restrict__ araw, const __bf16* __restrict__ wt,
    const int* __restrict__ edges, float* __restrict__ out)
{
    // P_t staging: [t][i(64)][e(64)] bf16, XOR-swizzled (element-index ^ ((i&7)<<3))
    __shared__ __bf16 Plds[NT * 64 * 64];

    const int it = blockIdx.x;   // 64-row i tile
    const int h  = blockIdx.y;
    const int b  = blockIdx.z;
    const int i0 = it * 64;

    const int tid  = threadIdx.x;
    const int w    = tid >> 6;   // wave 0..3, owns rows [w*16, w*16+16)
    const int l    = tid & 63;
    const int il   = l & 15;
    const int kg   = l >> 4;     // lane group 0..3
    const int row0 = w * 16;

    // ---------- Phase 1: P_t[i,e] = sum_dd s[i,dd] * W_t[dd,e] ----------
    // A-frags (src rows) are t/ntile-independent: preload both k-steps.
    const float* sbase = src + (size_t)(b * NN + i0 + row0 + il) * (NH * ND) + h * ND;
    bf16x8 af0 = load8f_bf16(sbase + 0 * 32 + kg * 8);
    bf16x8 af1 = load8f_bf16(sbase + 1 * 32 + kg * 8);

    #pragma unroll
    for (int t = 0; t < NT; ++t) {
        #pragma unroll
        for (int nt = 0; nt < 4; ++nt) {
            const int e = nt * 16 + il;
            f32x4 acc = {0.f, 0.f, 0.f, 0.f};
            #pragma unroll
            for (int ks = 0; ks < 2; ++ks) {
                bf16x8 bfrag;
                if constexpr (USE_WT) {
                    const __bf16* wp = wt + (((h * NT + t) * ND + e) * ND) + ks * 32 + kg * 8;
                    bfrag = *reinterpret_cast<const bf16x8*>(wp);
                } else {
                    #pragma unroll
                    for (int jj = 0; jj < 8; ++jj) {
                        const int dd = ks * 32 + kg * 8 + jj;
                        bfrag[jj] = (__bf16)araw[((size_t)(h * ND + dd) * ND + e) * NT + t];
                    }
                }
                bfrag = bfrag; // keep
                acc = (ks == 0)
                    ? __builtin_amdgcn_mfma_f32_16x16x32_bf16(af0, bfrag, acc, 0, 0, 0)
                    : __builtin_amdgcn_mfma_f32_16x16x32_bf16(af1, bfrag, acc, 0, 0, 0);
            }
            // C layout: col(e-dim)=lane&15, row(i-dim)=(lane>>4)*4+r  [m89/m91]
            #pragma unroll
            for (int r = 0; r < 4; ++r) {
                const int ip = row0 + kg * 4 + r;
                Plds[t * 4096 + ip * 64 + (e ^ ((ip & 7) << 3))] = (__bf16)acc[r];
            }
        }
    }

    __syncthreads();

    // ---------- Phase 2: S_t[i,j] = sum_e P_t[i,e] * dst[j,e] ----------
    // A-frags: P_t rows (row0+il), 8 contiguous e per lane; reused over all 16 j-tiles.
    bf16x8 pa[NT][2];
    {
        const int ip = row0 + il;
        #pragma unroll
        for (int t = 0; t < NT; ++t) {
            #pragma unroll
            for (int ks = 0; ks < 2; ++ks) {
                const int k = ks * 32 + kg * 8;
                pa[t][ks] = *reinterpret_cast<const bf16x8*>(
                    &Plds[t * 4096 + ip * 64 + (k ^ ((ip & 7) << 3))]);
            }
        }
    }

    const float* dbase = dst + (size_t)b * NN * (NH * ND) + h * ND;

    for (int jt = 0; jt < 16; ++jt) {
        const int j0 = jt * 16;
        const float* dp = dbase + (size_t)(j0 + il) * (NH * ND);
        bf16x8 bf0 = load8f_bf16(dp + 0 * 32 + kg * 8);
        bf16x8 bf1 = load8f_bf16(dp + 1 * 32 + kg * 8);

        f32x4 acc[NT];
        #pragma unroll
        for (int t = 0; t < NT; ++t) {
            acc[t] = (f32x4){0.f, 0.f, 0.f, 0.f};
            acc[t] = __builtin_amdgcn_mfma_f32_16x16x32_bf16(pa[t][0], bf0, acc[t], 0, 0, 0);
            acc[t] = __builtin_amdgcn_mfma_f32_16x16x32_bf16(pa[t][1], bf1, acc[t], 0, 0, 0);
        }

        #pragma unroll
        for (int r = 0; r < 4; ++r) {
            const int ig = i0 + row0 + kg * 4 + r;
            const int jg = j0 + il;
            const int ev = edges[((size_t)b * NN + ig) * NN + jg];
            float x;
            if (ev < 0) {
                x = -1e10f;
            } else {
                x = (ev == 0) ? acc[0][r]
                  : (ev == 1) ? acc[1][r]
                  : (ev == 2) ? acc[2][r]
                  : (ev == 3) ? acc[3][r]
                  :             acc[4][r];
            }
            x = (x >= 0.f) ? x : 0.2f * x;
            out[(((size_t)(b * NH + h)) * NN + ig) * NN + jg] = x;
        }
    }
}

extern "C" void kernel_launch(void* const* d_in, const int* in_sizes, int n_in,
                              void* d_out, int out_size, void* d_ws, size_t ws_size,
                              hipStream_t stream) {
    const float* src   = (const float*)d_in[0];
    const float* dst   = (const float*)d_in[1];
    const float* a     = (const float*)d_in[2];
    const int*   edges = (const int*)d_in[3];
    float* out = (float*)d_out;

    const size_t wt_bytes = (size_t)NH * NT * ND * ND * sizeof(__bf16);
    dim3 grid(NN / 64, NH, NB);

    if (ws_size >= wt_bytes) {
        __bf16* wt = (__bf16*)d_ws;
        const int total = NH * ND * ND * NT;
        prep_w_kernel<<<(total + 255) / 256, 256, 0, stream>>>(a, wt);
        mhea_kernel<true><<<grid, 256, 0, stream>>>(src, dst, a, wt, edges, out);
    } else {
        mhea_kernel<false><<<grid, 256, 0, stream>>>(src, dst, a, nullptr, edges, out);
    }
}

// Round 2
// 42.605 us; speedup vs baseline: 1.3611x; 1.3611x over previous
//
#include <hip/hip_runtime.h>
#include <hip/hip_bf16.h>

#define NB 16
#define NN 256
#define NH 8
#define ND 64
#define NT 5

typedef __bf16 bf16x8 __attribute__((ext_vector_type(8)));
typedef float  f32x4  __attribute__((ext_vector_type(4)));

__device__ __forceinline__ bf16x8 load8f_bf16(const float* __restrict__ p) {
    const float4 a = *reinterpret_cast<const float4*>(p);
    const float4 b = *reinterpret_cast<const float4*>(p + 4);
    bf16x8 r;
    r[0] = (__bf16)a.x; r[1] = (__bf16)a.y; r[2] = (__bf16)a.z; r[3] = (__bf16)a.w;
    r[4] = (__bf16)b.x; r[5] = (__bf16)b.y; r[6] = (__bf16)b.z; r[7] = (__bf16)b.w;
    return r;
}

// Transpose a[(h*64+dd)*64*5 + e*5 + t] (fp32) -> wt[h][t][e][dd] (bf16).
__global__ void prep_w_kernel(const float* __restrict__ a, __bf16* __restrict__ wt) {
    int idx = blockIdx.x * 256 + threadIdx.x;
    if (idx >= NH * ND * ND * NT) return;
    int t  = idx % NT;
    int e  = (idx / NT) % ND;
    int dd = (idx / (NT * ND)) % ND;
    int h  = idx / (NT * ND * ND);
    wt[(((h * NT + t) * ND + e) * ND) + dd] = (__bf16)a[idx];
}

template <bool USE_WT>
__global__ __launch_bounds__(512, 4) void mhea_kernel(
    const float* __restrict__ src, const float* __restrict__ dst,
    const float* __restrict__ araw, const __bf16* __restrict__ wt,
    const int* __restrict__ edges, float* __restrict__ out)
{
    // P_t staging: [t][i(32)][e(64)] bf16, XOR-swizzled (element-index ^ ((i&7)<<3))
    __shared__ __bf16 Plds[NT * 32 * 64];   // 20 KB

    const int it = blockIdx.x;   // 32-row i tile (8 tiles)
    const int h  = blockIdx.y;
    const int b  = blockIdx.z;
    const int i0 = it * 32;

    const int tid = threadIdx.x;
    const int w   = tid >> 6;    // wave 0..7
    const int l   = tid & 63;
    const int il  = l & 15;
    const int kg  = l >> 4;      // lane k-group 0..3

    // ---------- Phase 1: P_t[i,e] = sum_dd s[i,dd] * W_t[dd,e] ----------
    // wave w: i-band (w&1)*16, e-tile nt = w>>2? no: nt = w>>1 (4 values), band = w&1.
    const int band = w & 1;
    const int nt   = w >> 1;     // 0..3
    const int row0 = band * 16;

    const float* sbase = src + (size_t)(b * NN + i0 + row0 + il) * (NH * ND) + h * ND;
    bf16x8 af0 = load8f_bf16(sbase + kg * 8);
    bf16x8 af1 = load8f_bf16(sbase + 32 + kg * 8);

    const int e = nt * 16 + il;
    #pragma unroll
    for (int t = 0; t < NT; ++t) {
        bf16x8 b0, b1;
        if constexpr (USE_WT) {
            const __bf16* wp = wt + (((h * NT + t) * ND + e) * ND) + kg * 8;
            b0 = *reinterpret_cast<const bf16x8*>(wp);
            b1 = *reinterpret_cast<const bf16x8*>(wp + 32);
        } else {
            #pragma unroll
            for (int jj = 0; jj < 8; ++jj) {
                const int d0 = kg * 8 + jj;
                b0[jj] = (__bf16)araw[((size_t)(h * ND + d0) * ND + e) * NT + t];
                b1[jj] = (__bf16)araw[((size_t)(h * ND + d0 + 32) * ND + e) * NT + t];
            }
        }
        f32x4 acc = {0.f, 0.f, 0.f, 0.f};
        acc = __builtin_amdgcn_mfma_f32_16x16x32_bf16(af0, b0, acc, 0, 0, 0);
        acc = __builtin_amdgcn_mfma_f32_16x16x32_bf16(af1, b1, acc, 0, 0, 0);
        // C layout: col(e)=lane&15, row(i)=(lane>>4)*4+r  [m89/m91]
        #pragma unroll
        for (int r = 0; r < 4; ++r) {
            const int ip = row0 + kg * 4 + r;
            Plds[t * 2048 + ip * 64 + (e ^ ((ip & 7) << 3))] = (__bf16)acc[r];
        }
    }

    __syncthreads();

    // ---------- Phase 2: S_t[i,j] = sum_e P_t[i,e] * dst[j,e] ----------
    // wave w: i-band (w&1), j-quarter (w>>1)*64; 4 j-tiles of 16.
    const int jq    = w >> 1;
    const int jbase = jq * 64;
    const int ip    = row0 + il;

    bf16x8 pa[NT][2];
    #pragma unroll
    for (int t = 0; t < NT; ++t) {
        #pragma unroll
        for (int ks = 0; ks < 2; ++ks) {
            const int k = ks * 32 + kg * 8;
            pa[t][ks] = *reinterpret_cast<const bf16x8*>(
                &Plds[t * 2048 + ip * 64 + (k ^ ((ip & 7) << 3))]);
        }
    }

    const float* dbase = dst + (size_t)b * NN * (NH * ND) + h * ND;
    const int* ebase = edges + ((size_t)b * NN + i0 + row0 + kg * 4) * NN;

    // software pipeline: preload j-tile 0
    bf16x8 nb0, nb1;
    int ne0, ne1, ne2, ne3;
    {
        const float* dp = dbase + (size_t)(jbase + il) * (NH * ND);
        nb0 = load8f_bf16(dp + kg * 8);
        nb1 = load8f_bf16(dp + 32 + kg * 8);
        ne0 = ebase[0 * NN + jbase + il];
        ne1 = ebase[1 * NN + jbase + il];
        ne2 = ebase[2 * NN + jbase + il];
        ne3 = ebase[3 * NN + jbase + il];
    }

    #pragma unroll
    for (int jt = 0; jt < 4; ++jt) {
        const bf16x8 cb0 = nb0, cb1 = nb1;
        int ce[4] = {ne0, ne1, ne2, ne3};

        if (jt < 3) {
            const int j0n = jbase + (jt + 1) * 16;
            const float* dp = dbase + (size_t)(j0n + il) * (NH * ND);
            nb0 = load8f_bf16(dp + kg * 8);
            nb1 = load8f_bf16(dp + 32 + kg * 8);
            ne0 = ebase[0 * NN + j0n + il];
            ne1 = ebase[1 * NN + j0n + il];
            ne2 = ebase[2 * NN + j0n + il];
            ne3 = ebase[3 * NN + j0n + il];
        }

        f32x4 acc[NT];
        #pragma unroll
        for (int t = 0; t < NT; ++t) {
            acc[t] = (f32x4){0.f, 0.f, 0.f, 0.f};
            acc[t] = __builtin_amdgcn_mfma_f32_16x16x32_bf16(pa[t][0], cb0, acc[t], 0, 0, 0);
            acc[t] = __builtin_amdgcn_mfma_f32_16x16x32_bf16(pa[t][1], cb1, acc[t], 0, 0, 0);
        }

        #pragma unroll
        for (int r = 0; r < 4; ++r) {
            const int ig = i0 + row0 + kg * 4 + r;
            const int jg = jbase + jt * 16 + il;
            const int ev = ce[r];
            float x;
            if (ev < 0) {
                x = -1e10f;
            } else {
                x = (ev == 0) ? acc[0][r]
                  : (ev == 1) ? acc[1][r]
                  : (ev == 2) ? acc[2][r]
                  : (ev == 3) ? acc[3][r]
                  :             acc[4][r];
            }
            x = (x >= 0.f) ? x : 0.2f * x;
            out[(((size_t)(b * NH + h)) * NN + ig) * NN + jg] = x;
        }
    }
}

extern "C" void kernel_launch(void* const* d_in, const int* in_sizes, int n_in,
                              void* d_out, int out_size, void* d_ws, size_t ws_size,
                              hipStream_t stream) {
    const float* src   = (const float*)d_in[0];
    const float* dst   = (const float*)d_in[1];
    const float* a     = (const float*)d_in[2];
    const int*   edges = (const int*)d_in[3];
    float* out = (float*)d_out;

    const size_t wt_bytes = (size_t)NH * NT * ND * ND * sizeof(__bf16);
    dim3 grid(NN / 32, NH, NB);

    if (ws_size >= wt_bytes) {
        __bf16* wt = (__bf16*)d_ws;
        const int total = NH * ND * ND * NT;
        prep_w_kernel<<<(total + 255) / 256, 256, 0, stream>>>(a, wt);
        mhea_kernel<true><<<grid, 512, 0, stream>>>(src, dst, a, wt, edges, out);
    } else {
        mhea_kernel<false><<<grid, 512, 0, stream>>>(src, dst, a, nullptr, edges, out);
    }
}